// Round 5
// baseline (205.428 us; speedup 1.0000x reference)
//
#include <hip/hip_runtime.h>
#include <hip/hip_bf16.h>
#include <math.h>

using bf16 = __hip_bfloat16;

typedef __bf16 bf16x8 __attribute__((ext_vector_type(8)));
typedef __bf16 bf16x4 __attribute__((ext_vector_type(4)));
typedef float  f32x4  __attribute__((ext_vector_type(4)));
typedef float  f32x16 __attribute__((ext_vector_type(16)));

constexpr int Bb = 2;
constexpr int Ts = 2048;
constexpr int Cc = 1024;
constexpr int Hh = 16;
constexpr int Dh = 64;
constexpr int Mm = Bb * Ts;        // 4096 rows of x
constexpr int Nqkv = 3 * Cc;       // 3072
constexpr int BHTD = Bb * Hh * Ts * Dh;  // elements per Q/K/V tensor

// async global->LDS, 16B per lane; LDS dest = wave-uniform base + lane*16
__device__ __forceinline__
void gll16(const __bf16* g, __bf16* l)
{
    __builtin_amdgcn_global_load_lds(
        (const __attribute__((address_space(1))) unsigned int*)g,
        (__attribute__((address_space(3))) unsigned int*)l,
        16, 0, 0);
}

// ---------------------------------------------------------------------------
// Merged prep: [0,4096) cvt X fp32->bf16; [4096,4864) transpose W_qkv;
// [4864,5120) transpose W_proj.
// ---------------------------------------------------------------------------
__global__ __launch_bounds__(256)
void prep_all(const float* __restrict__ x, __bf16* __restrict__ Xb,
              const float* __restrict__ Wq, __bf16* __restrict__ Wqt,
              const float* __restrict__ Wp, __bf16* __restrict__ Wpt)
{
    __shared__ __bf16 tl[64][72];
    const int bid = blockIdx.x;
    const int t = threadIdx.x;

    if (bid < 4096) {
        int i = (bid * 256 + t) * 4;
        float4 v = *(const float4*)(x + i);
        bf16x4 o = { (__bf16)v.x, (__bf16)v.y, (__bf16)v.z, (__bf16)v.w };
        *(bf16x4*)(Xb + i) = o;
        return;
    }
    const float* W; __bf16* Wt; int cols, bx, by;
    if (bid < 4096 + 768) {
        W = Wq; Wt = Wqt; cols = Nqkv;
        bx = (bid - 4096) % 48; by = (bid - 4096) / 48;
    } else {
        W = Wp; Wt = Wpt; cols = Cc;
        bx = (bid - 4864) % 16; by = (bid - 4864) / 16;
    }
    const int c0 = bx * 64;   // N dim
    const int r0 = by * 64;   // K dim (1024)
    #pragma unroll
    for (int i = 0; i < 4; i++) {
        int e = t + 256 * i;
        int r = e >> 4, c4 = (e & 15) * 4;
        float4 v = *(const float4*)(W + (r0 + r) * cols + c0 + c4);
        bf16x4 o = { (__bf16)v.x, (__bf16)v.y, (__bf16)v.z, (__bf16)v.w };
        *(bf16x4*)&tl[r][c4] = o;
    }
    __syncthreads();
    #pragma unroll
    for (int i = 0; i < 4; i++) {
        int e = t + 256 * i;
        int n = e >> 4, k4 = (e & 15) * 4;
        bf16x4 o = { tl[k4][n], tl[k4 + 1][n], tl[k4 + 2][n], tl[k4 + 3][n] };
        *(bf16x4*)(Wt + (c0 + n) * 1024 + r0 + k4) = o;
    }
}

// ---------------------------------------------------------------------------
// MFMA GEMM core (R9-proven m97 structure), templated over BM (A-tile rows).
// BM=128: 4 waves x 64x64 (qkv, 3 blocks/CU). BM=64: 4 waves x 32x64
// (proj, 512-block grid -> 2 blocks/CU for cross-block overlap).
// BK=32, global_load_lds width-16 into unpadded LDS.
// C/D layout: col=l16, row=quad*4+r.
// ---------------------------------------------------------------------------
template<int BM>
__device__ __forceinline__
void gemm_core(const __bf16* __restrict__ A, const __bf16* __restrict__ Bt,
               int m0, int n0, int wm, int wn, int quad, int l16, int t,
               f32x4 (&acc)[4][4])
{
    __shared__ __bf16 Al[BM][32];
    __shared__ __bf16 Bl[128][32];

    constexpr int MT = BM / 32;        // m-subtiles per wave
    const int wave = t >> 6;
    const int lane = t & 63;
    const int srow = lane >> 2;        // 0..15
    const int scol = (lane & 3) * 8;   // 0,8,16,24

    const __bf16* Ag = A  + (size_t)(m0 + wave * 16 + srow) * 1024 + scol;
    const __bf16* Bg = Bt + (size_t)(n0 + wave * 16 + srow) * 1024 + scol;
    __bf16* Al_lo = &Al[wave * 16][0];
    __bf16* Bl_lo = &Bl[wave * 16][0];
    __bf16* Bl_hi = &Bl[64 + wave * 16][0];

    for (int k0 = 0; k0 < 1024; k0 += 32) {
        gll16(Ag + k0, Al_lo);
        if constexpr (BM == 128) {
            __bf16* Al_hi = &Al[64 + wave * 16][0];
            gll16(Ag + k0 + 64 * 1024, Al_hi);
        }
        gll16(Bg + k0,             Bl_lo);
        gll16(Bg + k0 + 64 * 1024, Bl_hi);
        __syncthreads();
        bf16x8 af[MT], bfr[4];
        #pragma unroll
        for (int mt = 0; mt < MT; mt++)
            af[mt] = *(const bf16x8*)&Al[wm * (BM / 2) + mt * 16 + l16][quad * 8];
        #pragma unroll
        for (int nt = 0; nt < 4; nt++)
            bfr[nt] = *(const bf16x8*)&Bl[wn * 64 + nt * 16 + l16][quad * 8];
        #pragma unroll
        for (int mt = 0; mt < MT; mt++)
            #pragma unroll
            for (int nt = 0; nt < 4; nt++)
                acc[mt][nt] = __builtin_amdgcn_mfma_f32_16x16x32_bf16(
                    af[mt], bfr[nt], acc[mt][nt], 0, 0, 0);
        __syncthreads();
    }
}

// QKV: bias + scatter. Q,K -> [B,H,T,Dh] via dedicated-LDS coalescing
// (bf16-typed wave-private buffer; NOT aliased with gemm staging);
// V -> [B,H,Dh,T] transposed, packed 8B direct stores.
__global__ __launch_bounds__(256)
void qkv_mfma(const __bf16* __restrict__ A, const __bf16* __restrict__ Bt,
              const float* __restrict__ bias, __bf16* __restrict__ qkv)
{
    __shared__ __bf16 ebuf[4][64][72];   // per-wave epilogue tile [m-row][d]

    const int t    = threadIdx.x;
    const int wave = t >> 6;
    const int lane = t & 63;
    const int quad = lane >> 4;
    const int l16  = lane & 15;
    const int wm   = wave >> 1, wn = wave & 1;
    const int n0 = blockIdx.x * 128;
    const int m0 = blockIdx.y * 128;

    f32x4 acc[4][4];
    #pragma unroll
    for (int i = 0; i < 4; i++)
        #pragma unroll
        for (int j = 0; j < 4; j++)
            acc[i][j] = f32x4{0.f, 0.f, 0.f, 0.f};

    gemm_core<128>(A, Bt, m0, n0, wm, wn, quad, l16, t, acc);

    // wave-uniform head info (wave n-range = 64 = one head's Dh)
    const int nw0 = n0 + wn * 64;
    const int which = nw0 >> 10;
    const int h = (nw0 & 1023) >> 6;

    if (which == 2) {
        // V^T: [b][h][d][tt], r=0..3 consecutive tt -> one 8B store
        #pragma unroll
        for (int nt = 0; nt < 4; nt++) {
            int d = nt * 16 + l16;
            float bs = bias[nw0 + nt * 16 + l16];
            #pragma unroll
            for (int mt = 0; mt < 4; mt++) {
                int m = m0 + wm * 64 + mt * 16 + quad * 4;
                int b = m >> 11;
                int tt = m & 2047;
                bf16x4 o = { (__bf16)(acc[mt][nt][0] + bs),
                             (__bf16)(acc[mt][nt][1] + bs),
                             (__bf16)(acc[mt][nt][2] + bs),
                             (__bf16)(acc[mt][nt][3] + bs) };
                *(bf16x4*)&qkv[2 * (size_t)BHTD +
                               (((size_t)(b * 16 + h) * 64 + d) * 2048 + tt)] = o;
            }
        }
    } else {
        // Q/K: stage wave's 64(m) x 64(d) tile in wave-private LDS,
        // then 8 coalesced 16B global stores per lane.
        #pragma unroll
        for (int nt = 0; nt < 4; nt++) {
            float bs = bias[nw0 + nt * 16 + l16];
            #pragma unroll
            for (int mt = 0; mt < 4; mt++)
                #pragma unroll
                for (int r = 0; r < 4; r++)
                    ebuf[wave][mt * 16 + quad * 4 + r][nt * 16 + l16] =
                        (__bf16)(acc[mt][nt][r] + bs);
        }
        // wave-private: compiler orders ds_write -> ds_read via lgkmcnt
        int m = m0 + wm * 64 + lane;
        int b = m >> 11;
        int tt = m & 2047;
        __bf16* dst = &qkv[which * (size_t)BHTD +
                           (((size_t)(b * 16 + h) * 2048 + tt) * 64)];
        #pragma unroll
        for (int c = 0; c < 8; c++)
            *(bf16x8*)(dst + c * 8) = *(const bf16x8*)&ebuf[wave][lane][c * 8];
    }
}

// Proj: bias + fp32 out [4096][1024]. BM=64 tile -> 512 blocks (2/CU).
__global__ __launch_bounds__(256)
void proj_mfma(const __bf16* __restrict__ A, const __bf16* __restrict__ Bt,
               const float* __restrict__ bias, float* __restrict__ out)
{
    const int t    = threadIdx.x;
    const int wave = t >> 6;
    const int lane = t & 63;
    const int quad = lane >> 4;
    const int l16  = lane & 15;
    const int wm   = wave >> 1, wn = wave & 1;
    const int n0 = blockIdx.x * 128;
    const int m0 = blockIdx.y * 64;

    f32x4 acc[4][4];
    #pragma unroll
    for (int i = 0; i < 4; i++)
        #pragma unroll
        for (int j = 0; j < 4; j++)
            acc[i][j] = f32x4{0.f, 0.f, 0.f, 0.f};

    gemm_core<64>(A, Bt, m0, n0, wm, wn, quad, l16, t, acc);

    #pragma unroll
    for (int nt = 0; nt < 4; nt++) {
        int n = n0 + wn * 64 + nt * 16 + l16;
        float bs = bias[n];
        #pragma unroll
        for (int mt = 0; mt < 2; mt++) {
            #pragma unroll
            for (int r = 0; r < 4; r++) {
                int m = m0 + wm * 32 + mt * 16 + quad * 4 + r;
                out[m * 1024 + n] = acc[mt][nt][r] + bs;
            }
        }
    }
}

// ===========================================================================
// MFMA flash attention v10 (R16): barrier-free, LDS-free, register-resident.
// 1024 independent waves (grid 256 x 4 waves); each wave owns 64 q rows
// (2x 32x32 subtiles) and streams the full 2048-k of its head.
// K/V MFMA fragments are 16B/lane contiguous IN GLOBAL MEMORY (K row = one
// 128B line; V^T chunk-col = one line) -> direct global->VGPR loads; L1
// (32KB) holds the 16KB/chunk working set; L2 holds per-head K/V (512KB,
// XCD-local: blocks of head h all land on XCD h%8 since grid=256, bh=blk&31).
// 1-chunk-deep software pipeline, 2x-unrolled with STATIC reg names
// (rule #20): loads lead use by ~1 chunk; QK^T(next) MFMAs fill the matrix
// pipe while softmax(cur) runs on VALU; PV(cur) follows. No barriers at all.
// Softmax: max-free (plain sum-exp2), in-register via cvt_pk + permlane32.
// ===========================================================================
__device__ __forceinline__
void ldk_g(const __bf16* __restrict__ Kb, int j, bf16x8 (&kf)[2][4])
{
    #pragma unroll
    for (int kt = 0; kt < 2; kt++)
        #pragma unroll
        for (int ds = 0; ds < 4; ds++)
            kf[kt][ds] = *(const bf16x8*)(Kb + ((size_t)j * 64 + kt * 32) * 64 + ds * 16);
}

__device__ __forceinline__
void ldv_g(const __bf16* __restrict__ Vb, int j, bf16x8 (&vf)[4][2])
{
    #pragma unroll
    for (int s = 0; s < 4; s++)
        #pragma unroll
        for (int dt = 0; dt < 2; dt++)
            vf[s][dt] = *(const bf16x8*)(Vb + (size_t)dt * 32 * Ts + j * 64 + s * 16);
}

__device__ __forceinline__
void qk_step(const bf16x8 (&kf)[2][4], const bf16x8 (&qf)[2][4], f32x16 (&st)[2][2])
{
    const f32x16 z16 = {0.f, 0.f, 0.f, 0.f, 0.f, 0.f, 0.f, 0.f,
                        0.f, 0.f, 0.f, 0.f, 0.f, 0.f, 0.f, 0.f};
    #pragma unroll
    for (int kt = 0; kt < 2; kt++)
        #pragma unroll
        for (int qs = 0; qs < 2; qs++) {
            f32x16 a;
            a = __builtin_amdgcn_mfma_f32_32x32x16_bf16(kf[kt][0], qf[qs][0], z16, 0, 0, 0);
            a = __builtin_amdgcn_mfma_f32_32x32x16_bf16(kf[kt][1], qf[qs][1], a, 0, 0, 0);
            a = __builtin_amdgcn_mfma_f32_32x32x16_bf16(kf[kt][2], qf[qs][2], a, 0, 0, 0);
            st[qs][kt] = __builtin_amdgcn_mfma_f32_32x32x16_bf16(kf[kt][3], qf[qs][3], a, 0, 0, 0);
        }
}

// exp2 + row-sum + pack to bf16 PV A-fragments (cvt_pk + permlane32_swap)
__device__ __forceinline__
void sm_step(f32x16 (&st)[2][2], bf16x8 (&pa)[2][4], float (&lsum)[2])
{
    #pragma unroll
    for (int qs = 0; qs < 2; qs++) {
        #pragma unroll
        for (int kt = 0; kt < 2; kt++) {
            float sum0 = 0.f, sum1 = 0.f;
            #pragma unroll
            for (int r = 0; r < 16; r++) {
                float pv = __builtin_amdgcn_exp2f(st[qs][kt][r]);
                st[qs][kt][r] = pv;
                if (r & 1) sum1 += pv; else sum0 += pv;
            }
            lsum[qs] += sum0 + sum1;
            #pragma unroll
            for (int s2 = 0; s2 < 2; s2++) {
                unsigned pk0, pk1, pk2, pk3;
                const int r4 = s2 * 8;
                asm("v_cvt_pk_bf16_f32 %0, %1, %2"
                    : "=v"(pk0) : "v"(st[qs][kt][r4 + 0]), "v"(st[qs][kt][r4 + 1]));
                asm("v_cvt_pk_bf16_f32 %0, %1, %2"
                    : "=v"(pk1) : "v"(st[qs][kt][r4 + 2]), "v"(st[qs][kt][r4 + 3]));
                asm("v_cvt_pk_bf16_f32 %0, %1, %2"
                    : "=v"(pk2) : "v"(st[qs][kt][r4 + 4]), "v"(st[qs][kt][r4 + 5]));
                asm("v_cvt_pk_bf16_f32 %0, %1, %2"
                    : "=v"(pk3) : "v"(st[qs][kt][r4 + 6]), "v"(st[qs][kt][r4 + 7]));
                asm("v_permlane32_swap_b32 %0, %1" : "+v"(pk0), "+v"(pk2));
                asm("v_permlane32_swap_b32 %0, %1" : "+v"(pk1), "+v"(pk3));
                union { unsigned u[4]; bf16x8 b; } pu;
                pu.u[0] = pk0; pu.u[1] = pk1; pu.u[2] = pk2; pu.u[3] = pk3;
                pa[qs][kt * 2 + s2] = pu.b;
            }
        }
    }
}

__device__ __forceinline__
void pv_step(const bf16x8 (&pa)[2][4], const bf16x8 (&vf)[4][2], f32x16 (&accO)[2][2])
{
    #pragma unroll
    for (int s = 0; s < 4; s++)
        #pragma unroll
        for (int dt = 0; dt < 2; dt++)
            #pragma unroll
            for (int qs = 0; qs < 2; qs++)
                accO[qs][dt] = __builtin_amdgcn_mfma_f32_32x32x16_bf16(
                    pa[qs][s], vf[s][dt], accO[qs][dt], 0, 0, 0);
}

__global__ __launch_bounds__(256, 1)
void attn_mfma(const __bf16* __restrict__ Q, const __bf16* __restrict__ K,
               const __bf16* __restrict__ VT, __bf16* __restrict__ O)
{
    const int t    = threadIdx.x;
    const int wave = t >> 6;
    const int lane = t & 63;
    const int c    = lane & 31;
    const int hi   = lane >> 5;

    const int blk = blockIdx.x;
    const int bh  = blk & 31;              // 32 ≡ 0 (mod 8): head stays XCD-local
    const int q0  = ((blk >> 5) * 4 + wave) * 64;

    const __bf16* Qp = Q  + ((size_t)bh * Ts + q0) * Dh;
    const __bf16* Kb = K  + (size_t)bh * Ts * Dh + (size_t)c * Dh + hi * 8;
    const __bf16* Vb = VT + (size_t)bh * Dh * Ts + (size_t)c * Ts + hi * 8;

    // Q fragments (B-operand of mfma(K,Q)), pre-scaled by log2e/sqrt(Dh)
    const float qscale = 0.125f * 1.44269504088896f;
    bf16x8 qf[2][4];
    #pragma unroll
    for (int qs = 0; qs < 2; qs++)
        #pragma unroll
        for (int ds = 0; ds < 4; ds++) {
            bf16x8 v = *(const bf16x8*)(Qp + (qs * 32 + c) * Dh + ds * 16 + hi * 8);
            #pragma unroll
            for (int i = 0; i < 8; i++) v[i] = (__bf16)(qscale * (float)v[i]);
            qf[qs][ds] = v;
        }

    f32x16 accO[2][2];
    #pragma unroll
    for (int qs = 0; qs < 2; qs++)
        #pragma unroll
        for (int dt = 0; dt < 2; dt++)
            #pragma unroll
            for (int i = 0; i < 16; i++) accO[qs][dt][i] = 0.f;
    float lsum[2] = {0.f, 0.f};

    // pipeline registers (static names; no dynamic indexing -> no scratch)
    bf16x8 kfE[2][4], kfO[2][4], vfE[4][2], vfO[4][2];
    f32x16 stE[2][2], stO[2][2];
    bf16x8 pa[2][4];

    // prologue: chunk 0 scores; K(1), V(0) in flight
    ldk_g(Kb, 0, kfE);
    qk_step(kfE, qf, stE);
    ldk_g(Kb, 1, kfO);
    ldv_g(Vb, 0, vfE);

    for (int i = 0; i < 15; i++) {
        const int e = 2 * i;
        ldk_g(Kb, e + 2, kfE);             // K(e+2): used this iter, loads lead
        qk_step(kfO, qf, stO);             // scores(e+1)       [matrix pipe]
        ldv_g(Vb, e + 1, vfO);             // V(e+1) in flight
        sm_step(stE, pa, lsum);            // softmax(e)        [VALU, overlaps]
        pv_step(pa, vfE, accO);            // PV(e)             [matrix pipe]
        ldk_g(Kb, e + 3, kfO);             // K(e+3) in flight
        qk_step(kfE, qf, stE);             // scores(e+2)
        ldv_g(Vb, e + 2, vfE);             // V(e+2) in flight
        sm_step(stO, pa, lsum);            // softmax(e+1)
        pv_step(pa, vfO, accO);            // PV(e+1)
    }
    // epilogue: chunks 30, 31
    qk_step(kfO, qf, stO);                 // scores(31)
    sm_step(stE, pa, lsum);
    pv_step(pa, vfE, accO);                // PV(30)
    ldv_g(Vb, 31, vfO);
    sm_step(stO, pa, lsum);
    pv_step(pa, vfO, accO);                // PV(31)

    // normalize + store [B,T,C]
    const int b = bh >> 4, h = bh & 15;
    #pragma unroll
    for (int qs = 0; qs < 2; qs++) {
        float l = lsum[qs] + __shfl_xor(lsum[qs], 32);   // full sum for q=qs*32+c
        float linv = 1.f / l;
        #pragma unroll
        for (int r = 0; r < 16; r++) {
            const int qrow = (r & 3) + 8 * (r >> 2) + 4 * hi;
            float inv = __shfl(linv, qrow);
            __bf16* Op = O + ((size_t)(b * Ts + q0 + qs * 32 + qrow)) * Cc +
                         h * 64 + c;
            Op[0]  = (__bf16)(accO[qs][0][r] * inv);
            Op[32] = (__bf16)(accO[qs][1][r] * inv);
        }
    }
}

// ---------------------------------------------------------------------------
extern "C" void kernel_launch(void* const* d_in, const int* in_sizes, int n_in,
                              void* d_out, int out_size, void* d_ws, size_t ws_size,
                              hipStream_t stream)
{
    (void)in_sizes; (void)n_in; (void)out_size; (void)ws_size;
    const float* x     = (const float*)d_in[0];
    const float* Wqkv  = (const float*)d_in[1];
    const float* bqkv  = (const float*)d_in[2];
    const float* Wproj = (const float*)d_in[3];
    const float* bproj = (const float*)d_in[4];
    float* out = (float*)d_out;

    __bf16* ws   = (__bf16*)d_ws;
    __bf16* Qw   = ws;                          // Q,K [B,H,T,Dh]; V^T [B,H,Dh,T]
    __bf16* XbAO = ws + 3 * (size_t)BHTD;       // Xb then AO (union)  8 MB
    __bf16* Wqt  = XbAO + (size_t)Mm * Cc;      // [3072][1024]        6 MB
    __bf16* Wpt  = Wqt + (size_t)Nqkv * Cc;     // [1024][1024]        2 MB

    prep_all<<<dim3(5120), 256, 0, stream>>>(x, XbAO, Wqkv, Wqt, Wproj, Wpt);
    qkv_mfma<<<dim3(Nqkv / 128, Mm / 128), 256, 0, stream>>>(XbAO, Wqt, bqkv, Qw);
    attn_mfma<<<dim3(256), 256, 0, stream>>>(
        Qw, Qw + BHTD, Qw + 2 * (size_t)BHTD, XbAO);   // AO overwrites Xb (dead)
    proj_mfma<<<dim3(Cc / 128, Mm / 64), 256, 0, stream>>>(XbAO, Wpt, bproj, out);
}